// Round 4
// baseline (3279.620 us; speedup 1.0000x reference)
//
#include <hip/hip_runtime.h>
#include <hip/hip_bf16.h>
#include <stdint.h>

#define B_ 32
#define T_ 128
#define V_ 32000
#define E_ 256
#define HID_ 512

typedef float f32x4 __attribute__((ext_vector_type(4)));
typedef __bf16 bf16x8 __attribute__((ext_vector_type(8)));

// RNE float -> bf16 bits
static __device__ __forceinline__ unsigned short f2bf(float f) {
    unsigned int u = __float_as_uint(f);
    unsigned int r = (u + 0x7fffu + ((u >> 16) & 1u)) >> 16;
    return (unsigned short)r;
}

// ---------------------------------------------------------------------------
// K1: C[(t*B+b), :] = emb[x[b,t]] @ I + b1   (all f32)
// ---------------------------------------------------------------------------
__global__ __launch_bounds__(512) void k_embed_proj(
    const int* __restrict__ x, const float* __restrict__ emb,
    const float* __restrict__ I, const float* __restrict__ b1,
    float* __restrict__ C) {
    __shared__ float e[16][E_];
    const int tid = threadIdx.x;
    const int row0 = blockIdx.x * 16;

#pragma unroll
    for (int p = 0; p < 2; ++p) {
        int flat = p * 2048 + tid * 4;
        int i = flat >> 8;
        int c = flat & 255;
        int r = row0 + i;           // global row = t*B + b
        int t = r >> 5, b = r & 31;
        int xi = x[b * T_ + t];
        *(f32x4*)&e[i][c] = *(const f32x4*)(emb + (size_t)xi * E_ + c);
    }
    __syncthreads();

    float acc[16];
#pragma unroll
    for (int i = 0; i < 16; ++i) acc[i] = 0.f;
    const int j = tid;

    for (int k4 = 0; k4 < E_ / 4; ++k4) {
        float Iv[4];
#pragma unroll
        for (int q = 0; q < 4; ++q) Iv[q] = I[(size_t)(k4 * 4 + q) * HID_ + j];
#pragma unroll
        for (int i = 0; i < 16; ++i) {
            f32x4 ev = *(const f32x4*)&e[i][k4 * 4];
            acc[i] += ev[0] * Iv[0];
            acc[i] += ev[1] * Iv[1];
            acc[i] += ev[2] * Iv[2];
            acc[i] += ev[3] * Iv[3];
        }
    }
    float bv = b1[j];
#pragma unroll
    for (int i = 0; i < 16; ++i)
        C[(size_t)(row0 + i) * HID_ + j] = acc[i] + bv;
}

// ---------------------------------------------------------------------------
// K2a: convert H (f32) -> bf16 bits
// ---------------------------------------------------------------------------
__global__ __launch_bounds__(256) void k_hconv(const float* __restrict__ H,
                                               unsigned short* __restrict__ Hb) {
    int idx = (blockIdx.x * 256 + threadIdx.x) * 4;
    f32x4 v = *(const f32x4*)(H + idx);
    unsigned int p0 = (unsigned)f2bf(v[0]) | ((unsigned)f2bf(v[1]) << 16);
    unsigned int p1 = (unsigned)f2bf(v[2]) | ((unsigned)f2bf(v[3]) << 16);
    uint2 pp; pp.x = p0; pp.y = p1;
    *(uint2*)(Hb + idx) = pp;
}

// ---------------------------------------------------------------------------
// K2b: transpose + convert U (f32 [512][32000]) -> Ut (bf16 [32000][512])
// ---------------------------------------------------------------------------
__global__ __launch_bounds__(256) void k_transpose(const float* __restrict__ U,
                                                   unsigned short* __restrict__ Ut) {
    __shared__ float tile[64][65];
    const int tid = threadIdx.x;
    const int n0 = blockIdx.x * 64;
    const int k0 = blockIdx.y * 64;
    const int c = tid & 63;
    const int r = tid >> 6;
#pragma unroll
    for (int it = 0; it < 16; ++it) {
        int kk = it * 4 + r;
        tile[kk][c] = U[(size_t)(k0 + kk) * V_ + n0 + c];
    }
    __syncthreads();
#pragma unroll
    for (int it = 0; it < 16; ++it) {
        int nn = it * 4 + r;
        Ut[(size_t)(n0 + nn) * HID_ + k0 + c] = f2bf(tile[c][nn]);
    }
}

// ---------------------------------------------------------------------------
// K3: recurrence, 4-WG k-split per batch row. grid = 128 (cooperative),
// block = 512. WG (b = blk>>2, g = blk&3) owns k-rows [g*128, g*128+128) of
// H, held in REGISTERS: thread j keeps H[k-slice][j] as 64 packed bf16 pairs.
// Per step: partial[j] = sum_{k in slice} h[g*128+k]*H[g*128+k][j],
// exchanged among the 4 WGs via agent-scope atomics in xbuf (t-indexed, no
// reuse) + per-(t,b,g) flags. All WGs redundantly compute h in canonical
// order (bitwise identical). h lives in LDS (2 KB).
// ---------------------------------------------------------------------------
__global__ __launch_bounds__(512) void k_recur(
    const float* __restrict__ C, const unsigned short* __restrict__ Hb,
    const float* __restrict__ init, unsigned short* __restrict__ hsb,
    float* __restrict__ lastState, float* __restrict__ xbuf,
    int* __restrict__ xflag) {
    __shared__ float h[HID_];
    __shared__ unsigned short stage[32][HID_];
    const int tid = threadIdx.x;
    const int b = blockIdx.x >> 2;
    const int g = blockIdx.x & 3;
    const int j = tid;

    // ---- prologue: load my H column-slice into registers (packed pairs) ----
    // Hreg[i] = H[g*128 + 2i][j] (lo 16) | H[g*128 + 2i + 1][j] (hi 16)
    unsigned int Hreg[64];
#pragma unroll
    for (int c4 = 0; c4 < 4; ++c4) {
        // stage 32 rows (32 KB) coalesced
#pragma unroll
        for (int i = 0; i < 4; ++i) {
            int idx = i * 512 + tid;          // uint4 index, 2048 total
            int rr = idx >> 6;                // 0..31
            int col = (idx & 63) * 8;
            *(uint4*)&stage[rr][col] =
                *(const uint4*)(Hb + (size_t)(g * 128 + c4 * 32 + rr) * HID_ + col);
        }
        __syncthreads();
#pragma unroll
        for (int rr = 0; rr < 32; rr += 2) {
            unsigned int lo = stage[rr][j];
            unsigned int hi = stage[rr + 1][j];
            Hreg[(c4 * 32 + rr) >> 1] = lo | (hi << 16);
        }
        __syncthreads();
    }

    if (tid < HID_) h[tid] = init[b * HID_ + tid];
    __syncthreads();

    for (int t = 0; t < T_; ++t) {
        float cv = C[((size_t)t * B_ + b) * HID_ + j];   // issue early
        // ---- MAC: partial over my k-slice, registers + LDS broadcast ----
        float acc = 0.f;
#pragma unroll
        for (int kb = 0; kb < 8; ++kb) {
            f32x4 hv[4];
#pragma unroll
            for (int q = 0; q < 4; ++q)
                hv[q] = *(const f32x4*)&h[g * 128 + kb * 16 + q * 4]; // slice base!
#pragma unroll
            for (int p = 0; p < 8; ++p) {
                unsigned int u = Hreg[kb * 8 + p];
                float hlo = hv[p >> 1][(2 * p) & 3];
                float hhi = hv[p >> 1][(2 * p + 1) & 3];
                acc += __uint_as_float(u << 16) * hlo;
                acc += __uint_as_float(u & 0xffff0000u) * hhi;
            }
        }

        // ---- exchange partials among the 4 WGs of this row ----
        const size_t base = ((size_t)t * B_ + b) * 4;
        __hip_atomic_store(&xbuf[(base + g) * HID_ + j], acc,
                           __ATOMIC_RELAXED, __HIP_MEMORY_SCOPE_AGENT);
        __threadfence();
        __syncthreads();
        if (tid == 0)
            __hip_atomic_store(&xflag[base + g], 1,
                               __ATOMIC_RELEASE, __HIP_MEMORY_SCOPE_AGENT);
        if (tid < 4 && tid != g) {
            while (__hip_atomic_load(&xflag[base + tid],
                                     __ATOMIC_ACQUIRE, __HIP_MEMORY_SCOPE_AGENT) == 0) {}
        }
        __syncthreads();

        // canonical order so every WG computes bitwise-identical h
        float v = cv;
#pragma unroll
        for (int gg = 0; gg < 4; ++gg) {
            float pg = (gg == g) ? acc
                     : __hip_atomic_load(&xbuf[(base + gg) * HID_ + j],
                                         __ATOMIC_RELAXED, __HIP_MEMORY_SCOPE_AGENT);
            v += pg;
        }
        v = fmaxf(v, 0.f);
        __syncthreads();          // all h-reads of this step done before write
        h[j] = v;
        if (g == 0)
            hsb[((size_t)t * B_ + b) * HID_ + j] = f2bf(v);
        __syncthreads();          // h visible for next step
    }
    if (g == 0) lastState[b * HID_ + j] = h[j];
}

// ---------------------------------------------------------------------------
// K4: logits = hs[4096x512](bf16) @ Ut^T (bf16 [N][K]) + b2  (unchanged)
// ---------------------------------------------------------------------------
#define LDK 72
__global__ __launch_bounds__(256) void k_gemm(
    const unsigned short* __restrict__ A, const unsigned short* __restrict__ Bt,
    const float* __restrict__ b2, float* __restrict__ out) {
    __shared__ unsigned short As[128 * LDK];
    __shared__ unsigned short Bs[128 * LDK];
    const int tid = threadIdx.x;
    const int l = tid & 63;
    const int w = tid >> 6;
    const int wm = w >> 1, wn = w & 1;
    const int n0 = blockIdx.x * 128;
    const int m0 = blockIdx.y * 128;

    f32x4 acc[4][4] = {};

    for (int kt = 0; kt < 8; ++kt) {
        const int kk = kt * 64;
        uint4 ra[4], rb[4];
#pragma unroll
        for (int i = 0; i < 4; ++i) {
            int flat = i * 256 + tid;
            int row = flat >> 3;
            int c8 = (flat & 7) * 8;
            ra[i] = *(const uint4*)(A + (size_t)(m0 + row) * HID_ + kk + c8);
            rb[i] = *(const uint4*)(Bt + (size_t)(n0 + row) * HID_ + kk + c8);
        }
        __syncthreads();
#pragma unroll
        for (int i = 0; i < 4; ++i) {
            int flat = i * 256 + tid;
            int row = flat >> 3;
            int c8 = (flat & 7) * 8;
            *(uint4*)(As + row * LDK + c8) = ra[i];
            *(uint4*)(Bs + row * LDK + c8) = rb[i];
        }
        __syncthreads();
#pragma unroll
        for (int ks = 0; ks < 2; ++ks) {
            bf16x8 af[4], bfr[4];
#pragma unroll
            for (int f = 0; f < 4; ++f) {
                af[f]  = *(const bf16x8*)(As + (wm * 64 + f * 16 + (l & 15)) * LDK + ks * 32 + (l >> 4) * 8);
                bfr[f] = *(const bf16x8*)(Bs + (wn * 64 + f * 16 + (l & 15)) * LDK + ks * 32 + (l >> 4) * 8);
            }
#pragma unroll
            for (int fm = 0; fm < 4; ++fm)
#pragma unroll
                for (int fn = 0; fn < 4; ++fn)
                    acc[fm][fn] = __builtin_amdgcn_mfma_f32_16x16x32_bf16(
                        af[fm], bfr[fn], acc[fm][fn], 0, 0, 0);
        }
    }

    const int cl = l & 15;
    const int q4 = (l >> 4) * 4;
    float b2v[4];
#pragma unroll
    for (int fn = 0; fn < 4; ++fn) b2v[fn] = b2[n0 + wn * 64 + fn * 16 + cl];
#pragma unroll
    for (int fm = 0; fm < 4; ++fm) {
#pragma unroll
        for (int r = 0; r < 4; ++r) {
            int rg = m0 + wm * 64 + fm * 16 + q4 + r; // A-row = t*B + b
            int t = rg >> 5, b = rg & 31;
            float* orow = out + (size_t)(b * T_ + t) * V_ + n0 + wn * 64 + cl;
#pragma unroll
            for (int fn = 0; fn < 4; ++fn)
                orow[fn * 16] = acc[fm][fn][r] + b2v[fn];
        }
    }
}

// ---------------------------------------------------------------------------
extern "C" void kernel_launch(void* const* d_in, const int* in_sizes, int n_in,
                              void* d_out, int out_size, void* d_ws, size_t ws_size,
                              hipStream_t stream) {
    const int* x      = (const int*)d_in[0];
    const float* init = (const float*)d_in[1];
    const float* emb  = (const float*)d_in[2];
    const float* H    = (const float*)d_in[3];
    const float* I    = (const float*)d_in[4];
    const float* b1   = (const float*)d_in[5];
    const float* U    = (const float*)d_in[6];
    const float* b2   = (const float*)d_in[7];
    float* out = (float*)d_out;

    // workspace layout:
    //   [0,8MB)     C      f32  [T*B][512]
    //   [8,12MB)    hsb    bf16 [T*B][512]
    //   [12,~45MB)  Ut     bf16 [32000][512]
    //   [46MB,..)   Hb     bf16 [512][512]   (512 KB)
    //   [47MB,..)   xflag  int  [T][B][4]    (64 KB, memset each call)
    char* ws = (char*)d_ws;
    float* C            = (float*)ws;
    unsigned short* hsb = (unsigned short*)(ws + ((size_t)8 << 20));
    unsigned short* Ut  = (unsigned short*)(ws + ((size_t)12 << 20));
    unsigned short* Hb  = (unsigned short*)(ws + ((size_t)46 << 20));
    int* xflag          = (int*)(ws + ((size_t)47 << 20));
    // partial-exchange buffer: lives in the logits region of d_out (33.5 MB);
    // k_gemm overwrites it afterwards.
    float* xbuf = out;
    float* lastState = out + (size_t)B_ * T_ * V_;

    hipMemsetAsync(xflag, 0, (size_t)T_ * B_ * 4 * sizeof(int), stream);
    k_embed_proj<<<256, 512, 0, stream>>>(x, emb, I, b1, C);
    k_hconv<<<(HID_ * HID_) / (256 * 4), 256, 0, stream>>>(H, Hb);
    k_transpose<<<dim3(500, 8), 256, 0, stream>>>(U, Ut);

    void* kargs[] = {(void*)&C, (void*)&Hb, (void*)&init, (void*)&hsb,
                     (void*)&lastState, (void*)&xbuf, (void*)&xflag};
    hipLaunchCooperativeKernel((void*)k_recur, dim3(128), dim3(512),
                               kargs, 0, stream);

    k_gemm<<<dim3(250, 32), 256, 0, stream>>>(hsb, Ut, b2, out);
}

// Round 5
// 2528.434 us; speedup vs baseline: 1.2971x; 1.2971x over previous
//
#include <hip/hip_runtime.h>
#include <hip/hip_bf16.h>
#include <stdint.h>

#define B_ 32
#define T_ 128
#define V_ 32000
#define E_ 256
#define HID_ 512

typedef float f32x4 __attribute__((ext_vector_type(4)));
typedef __bf16 bf16x8 __attribute__((ext_vector_type(8)));

// RNE float -> bf16 bits
static __device__ __forceinline__ unsigned short f2bf(float f) {
    unsigned int u = __float_as_uint(f);
    unsigned int r = (u + 0x7fffu + ((u >> 16) & 1u)) >> 16;
    return (unsigned short)r;
}

// ---------------------------------------------------------------------------
// K1: C[(t*B+b), :] = emb[x[b,t]] @ I + b1   (all f32)
// ---------------------------------------------------------------------------
__global__ __launch_bounds__(512) void k_embed_proj(
    const int* __restrict__ x, const float* __restrict__ emb,
    const float* __restrict__ I, const float* __restrict__ b1,
    float* __restrict__ C) {
    __shared__ float e[16][E_];
    const int tid = threadIdx.x;
    const int row0 = blockIdx.x * 16;

#pragma unroll
    for (int p = 0; p < 2; ++p) {
        int flat = p * 2048 + tid * 4;
        int i = flat >> 8;
        int c = flat & 255;
        int r = row0 + i;           // global row = t*B + b
        int t = r >> 5, b = r & 31;
        int xi = x[b * T_ + t];
        *(f32x4*)&e[i][c] = *(const f32x4*)(emb + (size_t)xi * E_ + c);
    }
    __syncthreads();

    float acc[16];
#pragma unroll
    for (int i = 0; i < 16; ++i) acc[i] = 0.f;
    const int j = tid;

    for (int k4 = 0; k4 < E_ / 4; ++k4) {
        float Iv[4];
#pragma unroll
        for (int q = 0; q < 4; ++q) Iv[q] = I[(size_t)(k4 * 4 + q) * HID_ + j];
#pragma unroll
        for (int i = 0; i < 16; ++i) {
            f32x4 ev = *(const f32x4*)&e[i][k4 * 4];
            acc[i] += ev[0] * Iv[0];
            acc[i] += ev[1] * Iv[1];
            acc[i] += ev[2] * Iv[2];
            acc[i] += ev[3] * Iv[3];
        }
    }
    float bv = b1[j];
#pragma unroll
    for (int i = 0; i < 16; ++i)
        C[(size_t)(row0 + i) * HID_ + j] = acc[i] + bv;
}

// ---------------------------------------------------------------------------
// K2a: pack H (f32 [512][512]) -> Hp (uint [256][512]):
// Hp[i][j] = bf16(H[2i][j]) | bf16(H[2i+1][j]) << 16
// ---------------------------------------------------------------------------
__global__ __launch_bounds__(256) void k_hpack(const float* __restrict__ H,
                                               unsigned int* __restrict__ Hp) {
    int idx = blockIdx.x * 256 + threadIdx.x;  // uint4 index
    int i = idx >> 7;            // packed row 0..255
    int j4 = (idx & 127) * 4;    // col
    f32x4 lo = *(const f32x4*)(H + (size_t)(2 * i) * HID_ + j4);
    f32x4 hi = *(const f32x4*)(H + (size_t)(2 * i + 1) * HID_ + j4);
    uint4 o;
    o.x = (unsigned)f2bf(lo[0]) | ((unsigned)f2bf(hi[0]) << 16);
    o.y = (unsigned)f2bf(lo[1]) | ((unsigned)f2bf(hi[1]) << 16);
    o.z = (unsigned)f2bf(lo[2]) | ((unsigned)f2bf(hi[2]) << 16);
    o.w = (unsigned)f2bf(lo[3]) | ((unsigned)f2bf(hi[3]) << 16);
    *(uint4*)(Hp + (size_t)i * HID_ + j4) = o;
}

// ---------------------------------------------------------------------------
// K2b: transpose + convert U (f32 [512][32000]) -> Ut (bf16 [32000][512])
// ---------------------------------------------------------------------------
__global__ __launch_bounds__(256) void k_transpose(const float* __restrict__ U,
                                                   unsigned short* __restrict__ Ut) {
    __shared__ float tile[64][65];
    const int tid = threadIdx.x;
    const int n0 = blockIdx.x * 64;
    const int k0 = blockIdx.y * 64;
    const int c = tid & 63;
    const int r = tid >> 6;
#pragma unroll
    for (int it = 0; it < 16; ++it) {
        int kk = it * 4 + r;
        tile[kk][c] = U[(size_t)(k0 + kk) * V_ + n0 + c];
    }
    __syncthreads();
#pragma unroll
    for (int it = 0; it < 16; ++it) {
        int nn = it * 4 + r;
        Ut[(size_t)(n0 + nn) * HID_ + k0 + c] = f2bf(tile[c][nn]);
    }
}

// ---------------------------------------------------------------------------
// K3: recurrence. 32 WGs (one per batch row) x 512 threads, NO cross-WG sync.
// H is CU-RESIDENT: thread j owns column j; rows 0..383 in 192 VGPRs
// (packed bf16 pairs), rows 384..511 in LDS Hl[64][512] (131 KB).
// Loaded once from Hp. Per step: 512 MACs/thread (unpack+fma, 4 accs),
// h (f32) broadcast from LDS. VALU-bound ~1.8 us/step.
// __launch_bounds__(512,2): 8 waves = 1 WG/CU, VGPR cap 256.
// ---------------------------------------------------------------------------
__global__ __launch_bounds__(512, 2) void k_recur(
    const float* __restrict__ C, const unsigned int* __restrict__ Hp,
    const float* __restrict__ init, unsigned short* __restrict__ hsb,
    float* __restrict__ lastState) {
    __shared__ float h[HID_];
    __shared__ unsigned int Hl[64][HID_];   // rows 384..511 packed
    const int tid = threadIdx.x;            // col j
    const int b = blockIdx.x;

    // ---- prologue: H column -> registers + LDS (one time) ----
    unsigned int Hreg[192];
#pragma unroll
    for (int i = 0; i < 192; ++i)
        Hreg[i] = Hp[(size_t)i * HID_ + tid];
#pragma unroll
    for (int p = 0; p < 64; ++p)
        Hl[p][tid] = Hp[(size_t)(192 + p) * HID_ + tid];

    h[tid] = init[b * HID_ + tid];
    __syncthreads();

    for (int t = 0; t < T_; ++t) {
        float cv = C[((size_t)t * B_ + b) * HID_ + tid];  // issue early
        float a0 = 0.f, a1 = 0.f, a2 = 0.f, a3 = 0.f;
        // ---- register part: rows 0..383 (uints 0..191) ----
#pragma unroll
        for (int q = 0; q < 48; ++q) {
            f32x4 h0 = *(const f32x4*)&h[q * 8];        // broadcast
            f32x4 h1 = *(const f32x4*)&h[q * 8 + 4];
            unsigned int u0 = Hreg[q * 4 + 0];
            unsigned int u1 = Hreg[q * 4 + 1];
            unsigned int u2 = Hreg[q * 4 + 2];
            unsigned int u3 = Hreg[q * 4 + 3];
            a0 += __uint_as_float(u0 << 16) * h0[0];
            a1 += __uint_as_float(u0 & 0xffff0000u) * h0[1];
            a2 += __uint_as_float(u1 << 16) * h0[2];
            a3 += __uint_as_float(u1 & 0xffff0000u) * h0[3];
            a0 += __uint_as_float(u2 << 16) * h1[0];
            a1 += __uint_as_float(u2 & 0xffff0000u) * h1[1];
            a2 += __uint_as_float(u3 << 16) * h1[2];
            a3 += __uint_as_float(u3 & 0xffff0000u) * h1[3];
        }
        // ---- LDS part: rows 384..511 (Hl[0..63]) ----
#pragma unroll
        for (int p = 0; p < 64; p += 2) {
            unsigned int u0 = Hl[p][tid];       // 2 lanes/bank: free
            unsigned int u1 = Hl[p + 1][tid];
            f32x4 hp = *(const f32x4*)&h[384 + 2 * p];  // 16B-aligned (p even)
            a0 += __uint_as_float(u0 << 16) * hp[0];
            a1 += __uint_as_float(u0 & 0xffff0000u) * hp[1];
            a2 += __uint_as_float(u1 << 16) * hp[2];
            a3 += __uint_as_float(u1 & 0xffff0000u) * hp[3];
        }
        float v = fmaxf(cv + ((a0 + a1) + (a2 + a3)), 0.f);
        __syncthreads();            // all h reads of this step done
        h[tid] = v;
        hsb[((size_t)t * B_ + b) * HID_ + tid] = f2bf(v);
        __syncthreads();            // h visible for next step
    }
    lastState[b * HID_ + tid] = h[tid];
}

// ---------------------------------------------------------------------------
// K4: logits = hs[4096x512](bf16) @ Ut^T (bf16 [N][K]) + b2  (unchanged)
// ---------------------------------------------------------------------------
#define LDK 72
__global__ __launch_bounds__(256) void k_gemm(
    const unsigned short* __restrict__ A, const unsigned short* __restrict__ Bt,
    const float* __restrict__ b2, float* __restrict__ out) {
    __shared__ unsigned short As[128 * LDK];
    __shared__ unsigned short Bs[128 * LDK];
    const int tid = threadIdx.x;
    const int l = tid & 63;
    const int w = tid >> 6;
    const int wm = w >> 1, wn = w & 1;
    const int n0 = blockIdx.x * 128;
    const int m0 = blockIdx.y * 128;

    f32x4 acc[4][4] = {};

    for (int kt = 0; kt < 8; ++kt) {
        const int kk = kt * 64;
        uint4 ra[4], rb[4];
#pragma unroll
        for (int i = 0; i < 4; ++i) {
            int flat = i * 256 + tid;
            int row = flat >> 3;
            int c8 = (flat & 7) * 8;
            ra[i] = *(const uint4*)(A + (size_t)(m0 + row) * HID_ + kk + c8);
            rb[i] = *(const uint4*)(Bt + (size_t)(n0 + row) * HID_ + kk + c8);
        }
        __syncthreads();
#pragma unroll
        for (int i = 0; i < 4; ++i) {
            int flat = i * 256 + tid;
            int row = flat >> 3;
            int c8 = (flat & 7) * 8;
            *(uint4*)(As + row * LDK + c8) = ra[i];
            *(uint4*)(Bs + row * LDK + c8) = rb[i];
        }
        __syncthreads();
#pragma unroll
        for (int ks = 0; ks < 2; ++ks) {
            bf16x8 af[4], bfr[4];
#pragma unroll
            for (int f = 0; f < 4; ++f) {
                af[f]  = *(const bf16x8*)(As + (wm * 64 + f * 16 + (l & 15)) * LDK + ks * 32 + (l >> 4) * 8);
                bfr[f] = *(const bf16x8*)(Bs + (wn * 64 + f * 16 + (l & 15)) * LDK + ks * 32 + (l >> 4) * 8);
            }
#pragma unroll
            for (int fm = 0; fm < 4; ++fm)
#pragma unroll
                for (int fn = 0; fn < 4; ++fn)
                    acc[fm][fn] = __builtin_amdgcn_mfma_f32_16x16x32_bf16(
                        af[fm], bfr[fn], acc[fm][fn], 0, 0, 0);
        }
    }

    const int cl = l & 15;
    const int q4 = (l >> 4) * 4;
    float b2v[4];
#pragma unroll
    for (int fn = 0; fn < 4; ++fn) b2v[fn] = b2[n0 + wn * 64 + fn * 16 + cl];
#pragma unroll
    for (int fm = 0; fm < 4; ++fm) {
#pragma unroll
        for (int r = 0; r < 4; ++r) {
            int rg = m0 + wm * 64 + fm * 16 + q4 + r; // A-row = t*B + b
            int t = rg >> 5, b = rg & 31;
            float* orow = out + (size_t)(b * T_ + t) * V_ + n0 + wn * 64 + cl;
#pragma unroll
            for (int fn = 0; fn < 4; ++fn)
                orow[fn * 16] = acc[fm][fn][r] + b2v[fn];
        }
    }
}

// ---------------------------------------------------------------------------
extern "C" void kernel_launch(void* const* d_in, const int* in_sizes, int n_in,
                              void* d_out, int out_size, void* d_ws, size_t ws_size,
                              hipStream_t stream) {
    const int* x      = (const int*)d_in[0];
    const float* init = (const float*)d_in[1];
    const float* emb  = (const float*)d_in[2];
    const float* H    = (const float*)d_in[3];
    const float* I    = (const float*)d_in[4];
    const float* b1   = (const float*)d_in[5];
    const float* U    = (const float*)d_in[6];
    const float* b2   = (const float*)d_in[7];
    float* out = (float*)d_out;

    // workspace layout:
    //   [0,8MB)     C      f32  [T*B][512]
    //   [8,12MB)    hsb    bf16 [T*B][512]
    //   [12,~45MB)  Ut     bf16 [32000][512]
    //   [46MB,..)   Hp     uint [256][512]  packed bf16 pairs (512 KB)
    char* ws = (char*)d_ws;
    float* C            = (float*)ws;
    unsigned short* hsb = (unsigned short*)(ws + ((size_t)8 << 20));
    unsigned short* Ut  = (unsigned short*)(ws + ((size_t)12 << 20));
    unsigned int* Hp    = (unsigned int*)(ws + ((size_t)46 << 20));
    float* lastState = out + (size_t)B_ * T_ * V_;

    k_embed_proj<<<256, 512, 0, stream>>>(x, emb, I, b1, C);
    k_hpack<<<128, 256, 0, stream>>>(H, Hp);
    k_transpose<<<dim3(500, 8), 256, 0, stream>>>(U, Ut);
    k_recur<<<B_, 512, 0, stream>>>(C, Hp, init, hsb, lastState);
    k_gemm<<<dim3(250, 32), 256, 0, stream>>>(hsb, Ut, b2, out);
}